// Round 1
// baseline (876.246 us; speedup 1.0000x reference)
//
#include <hip/hip_runtime.h>
#include <math.h>

// Problem constants (from reference)
#define BB    16
#define VN    256
#define QN    256
#define VD    512
#define QD    768
#define HK    1536   // H_DIM * K
#define HOUT  8
#define HDIM  512
#define KPOOL 3

// ---------------------------------------------------------------------------
// Mask kernel: one wave per row, outz[row] = (sum |x| == 0) ? 1 : 0
// ---------------------------------------------------------------------------
__global__ __launch_bounds__(64) void mask_kernel(const float* __restrict__ src,
                                                  int D, float* __restrict__ outz) {
    int row = blockIdx.x;
    int lane = threadIdx.x;
    const float* p = src + (size_t)row * D;
    float s = 0.f;
    for (int d = lane; d < D; d += 64) s += fabsf(p[d]);
    for (int off = 32; off > 0; off >>= 1) s += __shfl_down(s, off);
    s = __shfl(s, 0);
    if (lane == 0) outz[row] = (s == 0.f) ? 1.f : 0.f;
}

// ---------------------------------------------------------------------------
// C[m,n] = relu(sum_k A[m,k]*B[n,k] + bias[n])   (A:MxK row-major, B:NxK row-major)
// 64x64 tile, 256 threads, 4x4 micro-tile, BK=16
// ---------------------------------------------------------------------------
__global__ __launch_bounds__(256) void gemm_abt_bias_relu(
    const float* __restrict__ A, const float* __restrict__ Bm,
    const float* __restrict__ bias, float* __restrict__ C,
    int N, int K) {
    __shared__ float As[16][68];
    __shared__ float Bs[16][68];
    int m0 = blockIdx.y * 64, n0 = blockIdx.x * 64;
    int t = threadIdx.x, tx = t & 15, ty = t >> 4;
    float acc[4][4] = {};
    for (int k0 = 0; k0 < K; k0 += 16) {
        int idx = t * 4;
        int mm = idx >> 4;      // 0..63
        int kk = idx & 15;      // 0,4,8,12
        float4 av = *(const float4*)(A + (size_t)(m0 + mm) * K + k0 + kk);
        As[kk + 0][mm] = av.x; As[kk + 1][mm] = av.y;
        As[kk + 2][mm] = av.z; As[kk + 3][mm] = av.w;
        float4 bv = *(const float4*)(Bm + (size_t)(n0 + mm) * K + k0 + kk);
        Bs[kk + 0][mm] = bv.x; Bs[kk + 1][mm] = bv.y;
        Bs[kk + 2][mm] = bv.z; Bs[kk + 3][mm] = bv.w;
        __syncthreads();
#pragma unroll
        for (int k2 = 0; k2 < 16; ++k2) {
            float a[4], b[4];
#pragma unroll
            for (int i = 0; i < 4; ++i) a[i] = As[k2][ty * 4 + i];
#pragma unroll
            for (int j = 0; j < 4; ++j) b[j] = Bs[k2][tx * 4 + j];
#pragma unroll
            for (int i = 0; i < 4; ++i)
#pragma unroll
                for (int j = 0; j < 4; ++j) acc[i][j] += a[i] * b[j];
        }
        __syncthreads();
    }
#pragma unroll
    for (int i = 0; i < 4; ++i) {
        int m = m0 + ty * 4 + i;
#pragma unroll
        for (int j = 0; j < 4; ++j) {
            int n = n0 + tx * 4 + j;
            float x = acc[i][j] + bias[n];
            C[(size_t)m * N + n] = fmaxf(x, 0.f);
        }
    }
}

// ---------------------------------------------------------------------------
// att stage: per (b, head) with head 0..8.
//   head<8 : att[b,h,i,j] = sum_k hm[h,k]*v_[b,i,k]*q_[b,j,k] + hb[h]  -> d_out
//   head==8: A[b,i,j]     = sum_k (sum_h hm[h,k])*v_*q_ + sum_h hb[h] -> ws
// Masked entries -> -inf.
// ---------------------------------------------------------------------------
__global__ __launch_bounds__(256) void att_kernel(
    const float* __restrict__ v_, const float* __restrict__ q_,
    const float* __restrict__ hm, const float* __restrict__ hb,
    const float* __restrict__ vz, const float* __restrict__ qz,
    float* __restrict__ att_out, float* __restrict__ A_out) {
    __shared__ float As[16][68];
    __shared__ float Bs[16][68];
    __shared__ float ss[16];
    int bh = blockIdx.z;
    int b = bh / 9, h = bh - b * 9;
    const float* Va = v_ + (size_t)b * VN * HK;
    const float* Qa = q_ + (size_t)b * QN * HK;
    int m0 = blockIdx.y * 64, n0 = blockIdx.x * 64;
    int t = threadIdx.x, tx = t & 15, ty = t >> 4;
    float acc[4][4] = {};
    for (int k0 = 0; k0 < HK; k0 += 16) {
        if (t < 16) {
            float s;
            if (h < 8) {
                s = hm[h * HK + k0 + t];
            } else {
                s = 0.f;
#pragma unroll
                for (int hh = 0; hh < 8; ++hh) s += hm[hh * HK + k0 + t];
            }
            ss[t] = s;
        }
        int idx = t * 4;
        int mm = idx >> 4;
        int kk = idx & 15;
        float4 av = *(const float4*)(Va + (size_t)(m0 + mm) * HK + k0 + kk);
        As[kk + 0][mm] = av.x; As[kk + 1][mm] = av.y;
        As[kk + 2][mm] = av.z; As[kk + 3][mm] = av.w;
        float4 bv = *(const float4*)(Qa + (size_t)(n0 + mm) * HK + k0 + kk);
        Bs[kk + 0][mm] = bv.x; Bs[kk + 1][mm] = bv.y;
        Bs[kk + 2][mm] = bv.z; Bs[kk + 3][mm] = bv.w;
        __syncthreads();
#pragma unroll
        for (int k2 = 0; k2 < 16; ++k2) {
            float sv = ss[k2];
            float a[4], bq[4];
#pragma unroll
            for (int i = 0; i < 4; ++i) a[i] = As[k2][ty * 4 + i] * sv;
#pragma unroll
            for (int j = 0; j < 4; ++j) bq[j] = Bs[k2][tx * 4 + j];
#pragma unroll
            for (int i = 0; i < 4; ++i)
#pragma unroll
                for (int j = 0; j < 4; ++j) acc[i][j] += a[i] * bq[j];
        }
        __syncthreads();
    }
    float bias;
    if (h < 8) {
        bias = hb[h];
    } else {
        bias = 0.f;
#pragma unroll
        for (int hh = 0; hh < 8; ++hh) bias += hb[hh];
    }
#pragma unroll
    for (int i = 0; i < 4; ++i) {
        int i_ = m0 + ty * 4 + i;
        float vmask = vz[b * VN + i_];
#pragma unroll
        for (int j = 0; j < 4; ++j) {
            int j_ = n0 + tx * 4 + j;
            float x = acc[i][j] + bias;
            if (vmask != 0.f || qz[b * QN + j_] != 0.f) x = -INFINITY;
            if (h < 8)
                att_out[(((size_t)(b * 8 + h) * VN + i_) * QN) + j_] = x;
            else
                A_out[((size_t)b * VN + i_) * QN + j_] = x;
        }
    }
}

// ---------------------------------------------------------------------------
// T[b,i,k] = sum_j A[b,i,j] * q_[b,j,k]   (A: 256x256, q_: 256x1536, NT GEMM)
// ---------------------------------------------------------------------------
__global__ __launch_bounds__(256) void t_kernel(
    const float* __restrict__ Amat, const float* __restrict__ q_,
    float* __restrict__ T) {
    __shared__ float As[16][68];
    __shared__ float Bs[16][68];
    int b = blockIdx.z;
    const float* Ab = Amat + (size_t)b * VN * QN;
    const float* Qb = q_ + (size_t)b * QN * HK;
    int m0 = blockIdx.y * 64, n0 = blockIdx.x * 64;
    int t = threadIdx.x, tx = t & 15, ty = t >> 4;
    float acc[4][4] = {};
    for (int j0 = 0; j0 < QN; j0 += 16) {
        int idx = t * 4;
        int mm = idx >> 4;      // 0..63
        int jj = idx & 15;      // 0,4,8,12
        float4 av = *(const float4*)(Ab + (size_t)(m0 + mm) * QN + j0 + jj);
        As[jj + 0][mm] = av.x; As[jj + 1][mm] = av.y;
        As[jj + 2][mm] = av.z; As[jj + 3][mm] = av.w;
        int jj2 = idx >> 6;     // 0..15
        int nn = idx & 63;      // 0..60 step 4
        float4 bv = *(const float4*)(Qb + (size_t)(j0 + jj2) * HK + n0 + nn);
        Bs[jj2][nn + 0] = bv.x; Bs[jj2][nn + 1] = bv.y;
        Bs[jj2][nn + 2] = bv.z; Bs[jj2][nn + 3] = bv.w;
        __syncthreads();
#pragma unroll
        for (int k2 = 0; k2 < 16; ++k2) {
            float a[4], bq[4];
#pragma unroll
            for (int i = 0; i < 4; ++i) a[i] = As[k2][ty * 4 + i];
#pragma unroll
            for (int j = 0; j < 4; ++j) bq[j] = Bs[k2][tx * 4 + j];
#pragma unroll
            for (int i = 0; i < 4; ++i)
#pragma unroll
                for (int j = 0; j < 4; ++j) acc[i][j] += a[i] * bq[j];
        }
        __syncthreads();
    }
#pragma unroll
    for (int i = 0; i < 4; ++i) {
        int m = m0 + ty * 4 + i;
#pragma unroll
        for (int j = 0; j < 4; ++j) {
            int n = n0 + tx * 4 + j;
            T[((size_t)b * VN + m) * HK + n] = acc[i][j];
        }
    }
}

// ---------------------------------------------------------------------------
// lk[b,k] = sum_i v_[b,i,k] * T[b,i,k]
// ---------------------------------------------------------------------------
__global__ __launch_bounds__(256) void reduce_lk(
    const float* __restrict__ v_, const float* __restrict__ T,
    float* __restrict__ lk) {
    int b = blockIdx.y;
    int k = blockIdx.x * 256 + threadIdx.x;
    const float* vb = v_ + (size_t)b * VN * HK + k;
    const float* tb = T + (size_t)b * VN * HK + k;
    float acc = 0.f;
    for (int i = 0; i < VN; ++i) acc += vb[(size_t)i * HK] * tb[(size_t)i * HK];
    lk[b * HK + k] = acc;
}

// ---------------------------------------------------------------------------
// pool(k=3, sum) + BatchNorm (batch stats over b, biased var)
// one thread per feature d; batch dim fully in-register
// ---------------------------------------------------------------------------
__global__ __launch_bounds__(256) void bn_kernel(
    const float* __restrict__ lk, const float* __restrict__ gamma,
    const float* __restrict__ beta, float* __restrict__ out) {
    int d = blockIdx.x * blockDim.x + threadIdx.x;
    if (d >= HDIM) return;
    float l[BB];
    float mu = 0.f;
#pragma unroll
    for (int b = 0; b < BB; ++b) {
        const float* p = lk + b * HK + 3 * d;
        float s = p[0] + p[1] + p[2];
        l[b] = s;
        mu += s;
    }
    mu *= (1.f / BB);
    float var = 0.f;
#pragma unroll
    for (int b = 0; b < BB; ++b) {
        float dd = l[b] - mu;
        var += dd * dd;
    }
    var *= (1.f / BB);
    float inv = rsqrtf(var + 1e-5f);
    float g = gamma[d], be = beta[d];
#pragma unroll
    for (int b = 0; b < BB; ++b)
        out[b * HDIM + d] = (l[b] - mu) * inv * g + be;
}

// ---------------------------------------------------------------------------
extern "C" void kernel_launch(void* const* d_in, const int* in_sizes, int n_in,
                              void* d_out, int out_size, void* d_ws, size_t ws_size,
                              hipStream_t stream) {
    const float* v  = (const float*)d_in[0];
    const float* q  = (const float*)d_in[1];
    const float* Wv = (const float*)d_in[2];
    const float* bv = (const float*)d_in[3];
    const float* Wq = (const float*)d_in[4];
    const float* bq = (const float*)d_in[5];
    const float* hm = (const float*)d_in[6];
    const float* hb = (const float*)d_in[7];
    const float* gamma = (const float*)d_in[8];
    const float* beta  = (const float*)d_in[9];

    float* out_logits = (float*)d_out;                 // [16,512]
    float* out_att    = out_logits + BB * HDIM;        // [16,8,256,256]

    // workspace layout (floats)
    float* w   = (float*)d_ws;
    float* v_  = w;                       // 16*256*1536 = 6291456
    float* q_  = v_ + (size_t)BB * VN * HK;
    float* A   = q_ + (size_t)BB * QN * HK;            // 16*256*256
    float* T   = A + (size_t)BB * VN * QN;             // 16*256*1536
    float* lk  = T + (size_t)BB * VN * HK;             // 16*1536
    float* vz  = lk + BB * HK;                         // 4096
    float* qz  = vz + BB * VN;                         // 4096

    // 1. masks
    mask_kernel<<<BB * VN, 64, 0, stream>>>(v, VD, vz);
    mask_kernel<<<BB * QN, 64, 0, stream>>>(q, QD, qz);

    // 2. v_ = relu(v @ Wv^T + bv)   M=4096 N=1536 K=512
    gemm_abt_bias_relu<<<dim3(HK / 64, BB * VN / 64), 256, 0, stream>>>(
        v, Wv, bv, v_, HK, VD);
    // 3. q_ = relu(q @ Wq^T + bq)   M=4096 N=1536 K=768
    gemm_abt_bias_relu<<<dim3(HK / 64, BB * QN / 64), 256, 0, stream>>>(
        q, Wq, bq, q_, HK, QD);

    // 4. att (heads 0..7 -> d_out) + A = sum_h att (head 8 -> ws)
    att_kernel<<<dim3(QN / 64, VN / 64, BB * 9), 256, 0, stream>>>(
        v_, q_, hm, hb, vz, qz, out_att, A);

    // 5. T[b] = A[b] @ q_[b]
    t_kernel<<<dim3(HK / 64, VN / 64, BB), 256, 0, stream>>>(A, q_, T);

    // 6. lk[b,k] = sum_i v_[b,i,k]*T[b,i,k]
    reduce_lk<<<dim3(HK / 256, BB), 256, 0, stream>>>(v_, T, lk);

    // 7. pool + batchnorm -> logits
    bn_kernel<<<dim3((HDIM + 255) / 256), 256, 0, stream>>>(lk, gamma, beta, out_logits);
}

// Round 2
// 565.738 us; speedup vs baseline: 1.5489x; 1.5489x over previous
//
#include <hip/hip_runtime.h>
#include <math.h>

#define BB    16
#define VN    256
#define QN    256
#define VD    512
#define QD    768
#define HK    1536
#define HOUT  8
#define HDIM  512

typedef _Float16 half8 __attribute__((ext_vector_type(8)));
typedef float f32x4 __attribute__((ext_vector_type(4)));

// ---------------------------------------------------------------------------
// Mask kernel: one wave per row, outz[row] = (sum |x| == 0) ? 1 : 0
// ---------------------------------------------------------------------------
__global__ __launch_bounds__(64) void mask_kernel(const float* __restrict__ src,
                                                  int D, float* __restrict__ outz) {
    int row = blockIdx.x;
    int lane = threadIdx.x;
    const float* p = src + (size_t)row * D;
    float s = 0.f;
    for (int d = lane; d < D; d += 64) s += fabsf(p[d]);
    for (int off = 32; off > 0; off >>= 1) s += __shfl_down(s, off);
    s = __shfl(s, 0);
    if (lane == 0) outz[row] = (s == 0.f) ? 1.f : 0.f;
}

// ---------------------------------------------------------------------------
// hm (fp32) -> f16 per-head weights
// ---------------------------------------------------------------------------
__global__ __launch_bounds__(256) void conv_hm(const float* __restrict__ hm,
                                               _Float16* __restrict__ hs16) {
    int i = blockIdx.x * 256 + threadIdx.x;
    if (i < HOUT * HK) hs16[i] = (_Float16)hm[i];
}

// ---------------------------------------------------------------------------
// C[m,n] = relu(sum_k A[m,k]*B[n,k] + bias[n]); also emits f16 copy Ch.
// 64x64 tile, 256 threads, 4x4 micro-tile, BK=16  (fp32, logits-path quality)
// ---------------------------------------------------------------------------
__global__ __launch_bounds__(256) void gemm_abt_bias_relu(
    const float* __restrict__ A, const float* __restrict__ Bm,
    const float* __restrict__ bias, float* __restrict__ C,
    _Float16* __restrict__ Ch, int N, int K) {
    __shared__ float As[16][68];
    __shared__ float Bs[16][68];
    int m0 = blockIdx.y * 64, n0 = blockIdx.x * 64;
    int t = threadIdx.x, tx = t & 15, ty = t >> 4;
    float acc[4][4] = {};
    for (int k0 = 0; k0 < K; k0 += 16) {
        int idx = t * 4;
        int mm = idx >> 4;
        int kk = idx & 15;
        float4 av = *(const float4*)(A + (size_t)(m0 + mm) * K + k0 + kk);
        As[kk + 0][mm] = av.x; As[kk + 1][mm] = av.y;
        As[kk + 2][mm] = av.z; As[kk + 3][mm] = av.w;
        float4 bv = *(const float4*)(Bm + (size_t)(n0 + mm) * K + k0 + kk);
        Bs[kk + 0][mm] = bv.x; Bs[kk + 1][mm] = bv.y;
        Bs[kk + 2][mm] = bv.z; Bs[kk + 3][mm] = bv.w;
        __syncthreads();
#pragma unroll
        for (int k2 = 0; k2 < 16; ++k2) {
            float a[4], b[4];
#pragma unroll
            for (int i = 0; i < 4; ++i) a[i] = As[k2][ty * 4 + i];
#pragma unroll
            for (int j = 0; j < 4; ++j) b[j] = Bs[k2][tx * 4 + j];
#pragma unroll
            for (int i = 0; i < 4; ++i)
#pragma unroll
                for (int j = 0; j < 4; ++j) acc[i][j] += a[i] * b[j];
        }
        __syncthreads();
    }
#pragma unroll
    for (int i = 0; i < 4; ++i) {
        int m = m0 + ty * 4 + i;
#pragma unroll
        for (int j = 0; j < 4; ++j) {
            int n = n0 + tx * 4 + j;
            float x = acc[i][j] + bias[n];
            x = fmaxf(x, 0.f);
            C[(size_t)m * N + n] = x;
            Ch[(size_t)m * N + n] = (_Float16)x;
        }
    }
}

// ---------------------------------------------------------------------------
// att heads 0..7 via f16 MFMA: att[b,h,i,j] = sum_k (hm[h,k]*v_[i,k])*q_[j,k]+hb
// Block tile 128x64 (i x j), 4 waves, each wave 32x64 (2x4 16x16 frags).
// ---------------------------------------------------------------------------
__global__ __launch_bounds__(256) void att_mfma(
    const _Float16* __restrict__ v16, const _Float16* __restrict__ q16,
    const _Float16* __restrict__ hs16, const float* __restrict__ hb,
    const float* __restrict__ vz, const float* __restrict__ qz,
    float* __restrict__ att_out) {
    __shared__ _Float16 As[128 * 32];
    __shared__ _Float16 Bs[64 * 32];
    int z = blockIdx.z;
    int b = z >> 3, h = z & 7;
    int i0 = blockIdx.y * 128, j0 = blockIdx.x * 64;
    int t = threadIdx.x;
    int w = t >> 6, ln = t & 63, quad = ln >> 4, r16 = ln & 15;
    const _Float16* Vb = v16 + (size_t)b * VN * HK;
    const _Float16* Qb = q16 + (size_t)b * QN * HK;
    const _Float16* Hs = hs16 + (size_t)h * HK;
    int amm = t >> 1, aseg = t & 1;   // A: 128 rows x 4 segs (2 per thread)
    int bmm = t >> 2, bseg = t & 3;   // B: 64 rows x 4 segs
    f32x4 acc[2][4] = {};
    for (int k0 = 0; k0 < HK; k0 += 32) {
        half8 a0 = *(const half8*)(Vb + (size_t)(i0 + amm) * HK + k0 + aseg * 8);
        half8 a1 = *(const half8*)(Vb + (size_t)(i0 + amm) * HK + k0 + (aseg + 2) * 8);
        half8 h0 = *(const half8*)(Hs + k0 + aseg * 8);
        half8 h1 = *(const half8*)(Hs + k0 + (aseg + 2) * 8);
        half8 bv = *(const half8*)(Qb + (size_t)(j0 + bmm) * HK + k0 + bseg * 8);
        a0 *= h0;
        a1 *= h1;
        __syncthreads();   // previous compute phase done before overwrite
        *(half8*)&As[amm * 32 + aseg * 8] = a0;
        *(half8*)&As[amm * 32 + (aseg + 2) * 8] = a1;
        *(half8*)&Bs[bmm * 32 + bseg * 8] = bv;
        __syncthreads();
        half8 af[2], bf[4];
#pragma unroll
        for (int fi = 0; fi < 2; ++fi)
            af[fi] = *(const half8*)&As[(w * 32 + fi * 16 + r16) * 32 + quad * 8];
#pragma unroll
        for (int fj = 0; fj < 4; ++fj)
            bf[fj] = *(const half8*)&Bs[(fj * 16 + r16) * 32 + quad * 8];
#pragma unroll
        for (int fi = 0; fi < 2; ++fi)
#pragma unroll
            for (int fj = 0; fj < 4; ++fj)
                acc[fi][fj] = __builtin_amdgcn_mfma_f32_16x16x32_f16(
                    af[fi], bf[fj], acc[fi][fj], 0, 0, 0);
    }
    float hbv = hb[h];
    float* outb = att_out + ((size_t)(b * 8 + h)) * VN * QN;
#pragma unroll
    for (int fi = 0; fi < 2; ++fi) {
#pragma unroll
        for (int r = 0; r < 4; ++r) {
            int i = i0 + w * 32 + fi * 16 + quad * 4 + r;
            float vm = vz[b * VN + i];
#pragma unroll
            for (int fj = 0; fj < 4; ++fj) {
                int j = j0 + fj * 16 + r16;
                float x = acc[fi][fj][r] + hbv;
                if (vm != 0.f || qz[b * QN + j] != 0.f) x = -INFINITY;
                outb[(size_t)i * QN + j] = x;
            }
        }
    }
}

// ---------------------------------------------------------------------------
// A[b,i,j] = sum_k (sum_h hm[h,k]) * v_[b,i,k] * q_[b,j,k]   (fp32, split-K=4,
// atomicAdd). Bias + mask applied downstream in t_kernel.
// ---------------------------------------------------------------------------
__global__ __launch_bounds__(256) void a_gemm_splitk(
    const float* __restrict__ v_, const float* __restrict__ q_,
    const float* __restrict__ hm, float* __restrict__ A_out) {
    __shared__ float As[16][68];
    __shared__ float Bs[16][68];
    __shared__ float ss[16];
    int z = blockIdx.z;
    int b = z >> 2, kc = z & 3;
    const float* Va = v_ + (size_t)b * VN * HK;
    const float* Qa = q_ + (size_t)b * QN * HK;
    int m0 = blockIdx.y * 64, n0 = blockIdx.x * 64;
    int t = threadIdx.x, tx = t & 15, ty = t >> 4;
    float acc[4][4] = {};
    int kbeg = kc * (HK / 4), kend = kbeg + HK / 4;
    for (int k0 = kbeg; k0 < kend; k0 += 16) {
        if (t < 16) {
            float s = 0.f;
#pragma unroll
            for (int hh = 0; hh < 8; ++hh) s += hm[hh * HK + k0 + t];
            ss[t] = s;
        }
        int idx = t * 4;
        int mm = idx >> 4;
        int kk = idx & 15;
        float4 av = *(const float4*)(Va + (size_t)(m0 + mm) * HK + k0 + kk);
        As[kk + 0][mm] = av.x; As[kk + 1][mm] = av.y;
        As[kk + 2][mm] = av.z; As[kk + 3][mm] = av.w;
        float4 bv = *(const float4*)(Qa + (size_t)(n0 + mm) * HK + k0 + kk);
        Bs[kk + 0][mm] = bv.x; Bs[kk + 1][mm] = bv.y;
        Bs[kk + 2][mm] = bv.z; Bs[kk + 3][mm] = bv.w;
        __syncthreads();
#pragma unroll
        for (int k2 = 0; k2 < 16; ++k2) {
            float sv = ss[k2];
            float a[4], bq[4];
#pragma unroll
            for (int i = 0; i < 4; ++i) a[i] = As[k2][ty * 4 + i] * sv;
#pragma unroll
            for (int j = 0; j < 4; ++j) bq[j] = Bs[k2][tx * 4 + j];
#pragma unroll
            for (int i = 0; i < 4; ++i)
#pragma unroll
                for (int j = 0; j < 4; ++j) acc[i][j] += a[i] * bq[j];
        }
        __syncthreads();
    }
#pragma unroll
    for (int i = 0; i < 4; ++i) {
        int m = m0 + ty * 4 + i;
#pragma unroll
        for (int j = 0; j < 4; ++j) {
            int n = n0 + tx * 4 + j;
            atomicAdd(&A_out[((size_t)b * VN + m) * QN + n], acc[i][j]);
        }
    }
}

// ---------------------------------------------------------------------------
// T[b,i,k] = sum_j (A[b,i,j]+bias8 masked) * q_[b,j,k]
// ---------------------------------------------------------------------------
__global__ __launch_bounds__(256) void t_kernel(
    const float* __restrict__ Amat, const float* __restrict__ q_,
    const float* __restrict__ hb, const float* __restrict__ vz,
    const float* __restrict__ qz, float* __restrict__ T) {
    __shared__ float As[16][68];
    __shared__ float Bs[16][68];
    int b = blockIdx.z;
    const float* Ab = Amat + (size_t)b * VN * QN;
    const float* Qb = q_ + (size_t)b * QN * HK;
    int m0 = blockIdx.y * 64, n0 = blockIdx.x * 64;
    int t = threadIdx.x, tx = t & 15, ty = t >> 4;
    float bias8 = 0.f;
#pragma unroll
    for (int hh = 0; hh < 8; ++hh) bias8 += hb[hh];
    float acc[4][4] = {};
    for (int j0 = 0; j0 < QN; j0 += 16) {
        int idx = t * 4;
        int mm = idx >> 4;
        int jj = idx & 15;
        float4 av = *(const float4*)(Ab + (size_t)(m0 + mm) * QN + j0 + jj);
        float vm = vz[b * VN + m0 + mm];
        float e0 = av.x + bias8, e1 = av.y + bias8, e2 = av.z + bias8, e3 = av.w + bias8;
        if (vm != 0.f || qz[b * QN + j0 + jj + 0] != 0.f) e0 = -INFINITY;
        if (vm != 0.f || qz[b * QN + j0 + jj + 1] != 0.f) e1 = -INFINITY;
        if (vm != 0.f || qz[b * QN + j0 + jj + 2] != 0.f) e2 = -INFINITY;
        if (vm != 0.f || qz[b * QN + j0 + jj + 3] != 0.f) e3 = -INFINITY;
        As[jj + 0][mm] = e0; As[jj + 1][mm] = e1;
        As[jj + 2][mm] = e2; As[jj + 3][mm] = e3;
        int jj2 = idx >> 6;
        int nn = idx & 63;
        float4 bv = *(const float4*)(Qb + (size_t)(j0 + jj2) * HK + n0 + nn);
        Bs[jj2][nn + 0] = bv.x; Bs[jj2][nn + 1] = bv.y;
        Bs[jj2][nn + 2] = bv.z; Bs[jj2][nn + 3] = bv.w;
        __syncthreads();
#pragma unroll
        for (int k2 = 0; k2 < 16; ++k2) {
            float a[4], bq[4];
#pragma unroll
            for (int i = 0; i < 4; ++i) a[i] = As[k2][ty * 4 + i];
#pragma unroll
            for (int j = 0; j < 4; ++j) bq[j] = Bs[k2][tx * 4 + j];
#pragma unroll
            for (int i = 0; i < 4; ++i)
#pragma unroll
                for (int j = 0; j < 4; ++j) acc[i][j] += a[i] * bq[j];
        }
        __syncthreads();
    }
#pragma unroll
    for (int i = 0; i < 4; ++i) {
        int m = m0 + ty * 4 + i;
#pragma unroll
        for (int j = 0; j < 4; ++j) {
            int n = n0 + tx * 4 + j;
            T[((size_t)b * VN + m) * HK + n] = acc[i][j];
        }
    }
}

// ---------------------------------------------------------------------------
// lk[b,k] = sum_i v_[b,i,k] * T[b,i,k]
// ---------------------------------------------------------------------------
__global__ __launch_bounds__(256) void reduce_lk(
    const float* __restrict__ v_, const float* __restrict__ T,
    float* __restrict__ lk) {
    int b = blockIdx.y;
    int k = blockIdx.x * 256 + threadIdx.x;
    const float* vb = v_ + (size_t)b * VN * HK + k;
    const float* tb = T + (size_t)b * VN * HK + k;
    float acc = 0.f;
    for (int i = 0; i < VN; ++i) acc += vb[(size_t)i * HK] * tb[(size_t)i * HK];
    lk[b * HK + k] = acc;
}

// ---------------------------------------------------------------------------
// pool(k=3, sum) + BatchNorm (batch stats, biased var)
// ---------------------------------------------------------------------------
__global__ __launch_bounds__(256) void bn_kernel(
    const float* __restrict__ lk, const float* __restrict__ gamma,
    const float* __restrict__ beta, float* __restrict__ out) {
    int d = blockIdx.x * blockDim.x + threadIdx.x;
    if (d >= HDIM) return;
    float l[BB];
    float mu = 0.f;
#pragma unroll
    for (int b = 0; b < BB; ++b) {
        const float* p = lk + b * HK + 3 * d;
        float s = p[0] + p[1] + p[2];
        l[b] = s;
        mu += s;
    }
    mu *= (1.f / BB);
    float var = 0.f;
#pragma unroll
    for (int b = 0; b < BB; ++b) {
        float dd = l[b] - mu;
        var += dd * dd;
    }
    var *= (1.f / BB);
    float inv = rsqrtf(var + 1e-5f);
    float g = gamma[d], be = beta[d];
#pragma unroll
    for (int b = 0; b < BB; ++b)
        out[b * HDIM + d] = (l[b] - mu) * inv * g + be;
}

// ---------------------------------------------------------------------------
extern "C" void kernel_launch(void* const* d_in, const int* in_sizes, int n_in,
                              void* d_out, int out_size, void* d_ws, size_t ws_size,
                              hipStream_t stream) {
    const float* v  = (const float*)d_in[0];
    const float* q  = (const float*)d_in[1];
    const float* Wv = (const float*)d_in[2];
    const float* bv = (const float*)d_in[3];
    const float* Wq = (const float*)d_in[4];
    const float* bq = (const float*)d_in[5];
    const float* hm = (const float*)d_in[6];
    const float* hb = (const float*)d_in[7];
    const float* gamma = (const float*)d_in[8];
    const float* beta  = (const float*)d_in[9];

    float* out_logits = (float*)d_out;
    float* out_att    = out_logits + BB * HDIM;

    // workspace layout
    float* w   = (float*)d_ws;
    float* v_  = w;                                   // 6291456 f32
    float* q_  = v_ + (size_t)BB * VN * HK;           // 6291456 f32
    float* A   = q_ + (size_t)BB * QN * HK;           // 1048576 f32
    float* T   = A + (size_t)BB * VN * QN;            // 6291456 f32 (aliases v16/q16)
    _Float16* v16 = (_Float16*)T;                     // 6291456 f16
    _Float16* q16 = v16 + (size_t)BB * VN * HK;       // 6291456 f16
    float* lk  = T + (size_t)BB * VN * HK;
    float* vz  = lk + BB * HK;
    float* qz  = vz + BB * VN;
    _Float16* hs16 = (_Float16*)(qz + BB * QN);       // 8*1536 f16

    hipMemsetAsync(A, 0, (size_t)BB * VN * QN * sizeof(float), stream);

    // masks + f16 head weights
    mask_kernel<<<BB * VN, 64, 0, stream>>>(v, VD, vz);
    mask_kernel<<<BB * QN, 64, 0, stream>>>(q, QD, qz);
    conv_hm<<<(HOUT * HK + 255) / 256, 256, 0, stream>>>(hm, hs16);

    // v_ / q_ projections (fp32 + f16 copy)
    gemm_abt_bias_relu<<<dim3(HK / 64, BB * VN / 64), 256, 0, stream>>>(
        v, Wv, bv, v_, v16, HK, VD);
    gemm_abt_bias_relu<<<dim3(HK / 64, BB * QN / 64), 256, 0, stream>>>(
        q, Wq, bq, q_, q16, HK, QD);

    // att heads 0..7 (f16 MFMA) -> d_out
    att_mfma<<<dim3(QN / 64, VN / 128, BB * 8), 256, 0, stream>>>(
        v16, q16, hs16, hb, vz, qz, out_att);

    // A = combined-head attention (fp32, split-K atomics)
    a_gemm_splitk<<<dim3(QN / 64, VN / 64, BB * 4), 256, 0, stream>>>(v_, q_, hm, A);

    // T[b] = (A+bias, masked) @ q_[b]
    t_kernel<<<dim3(HK / 64, VN / 64, BB), 256, 0, stream>>>(A, q_, hb, vz, qz, T);

    // lk + pool + BN
    reduce_lk<<<dim3(HK / 256, BB), 256, 0, stream>>>(v_, T, lk);
    bn_kernel<<<dim3((HDIM + 255) / 256), 256, 0, stream>>>(lk, gamma, beta, out_logits);
}

// Round 3
// 244.745 us; speedup vs baseline: 3.5802x; 2.3115x over previous
//
#include <hip/hip_runtime.h>
#include <math.h>

#define BB    16
#define VN    256
#define QN    256
#define VD    512
#define QD    768
#define HK    1536
#define HOUT  8
#define HDIM  512

typedef _Float16 half8 __attribute__((ext_vector_type(8)));
typedef _Float16 half4 __attribute__((ext_vector_type(4)));
typedef float f32x4 __attribute__((ext_vector_type(4)));

// ---------------------------------------------------------------------------
// fp32 -> f16 elementwise (n divisible by 4)
// ---------------------------------------------------------------------------
__global__ __launch_bounds__(256) void f32_to_f16_vec(const float* __restrict__ src,
                                                      _Float16* __restrict__ dst, int n4) {
    int i = blockIdx.x * 256 + threadIdx.x;
    if (i < n4) {
        float4 v = ((const float4*)src)[i];
        half4 h = {(_Float16)v.x, (_Float16)v.y, (_Float16)v.z, (_Float16)v.w};
        ((half4*)dst)[i] = h;
    }
}

// hm fp32 [8][HK] -> hs16 [9][HK] f16, row 8 = sum of rows 0..7
__global__ __launch_bounds__(256) void conv_hm9(const float* __restrict__ hm,
                                                _Float16* __restrict__ hs16) {
    int k = blockIdx.x * 256 + threadIdx.x;
    if (k >= HK) return;
    float s = 0.f;
#pragma unroll
    for (int h = 0; h < 8; ++h) {
        float x = hm[h * HK + k];
        s += x;
        hs16[h * HK + k] = (_Float16)x;
    }
    hs16[8 * HK + k] = (_Float16)s;
}

// ---------------------------------------------------------------------------
// Mask kernel: one wave per row, outz[row] = (sum |x| == 0) ? 1 : 0
// ---------------------------------------------------------------------------
__global__ __launch_bounds__(64) void mask_kernel(const float* __restrict__ src,
                                                  int D, float* __restrict__ outz) {
    int row = blockIdx.x;
    int lane = threadIdx.x;
    const float* p = src + (size_t)row * D;
    float s = 0.f;
    for (int d = lane; d < D; d += 64) s += fabsf(p[d]);
    for (int off = 32; off > 0; off >>= 1) s += __shfl_down(s, off);
    s = __shfl(s, 0);
    if (lane == 0) outz[row] = (s == 0.f) ? 1.f : 0.f;
}

// ---------------------------------------------------------------------------
// Projection: C16[m,n] = (f16) relu(sum_k A16[m,k]*W16[n,k] + bias[n])
// Block 128m x 64n, 4 waves (wave: 32m x 64n = 2x4 16x16x32 frags), BK=32.
// ---------------------------------------------------------------------------
__global__ __launch_bounds__(256) void proj_mfma(
    const _Float16* __restrict__ A16, const _Float16* __restrict__ W16,
    const float* __restrict__ bias, _Float16* __restrict__ C16, int K) {
    __shared__ _Float16 As[128 * 32];
    __shared__ _Float16 Bs[64 * 32];
    int m0 = blockIdx.y * 128, n0 = blockIdx.x * 64;
    int t = threadIdx.x;
    int w = t >> 6, ln = t & 63, quad = ln >> 4, r16 = ln & 15;
    int amm = t >> 1, aseg = t & 1;
    int bmm = t >> 2, bseg = t & 3;
    f32x4 acc[2][4] = {};
    for (int k0 = 0; k0 < K; k0 += 32) {
        half8 a0 = *(const half8*)(A16 + (size_t)(m0 + amm) * K + k0 + aseg * 8);
        half8 a1 = *(const half8*)(A16 + (size_t)(m0 + amm) * K + k0 + (aseg + 2) * 8);
        half8 bv = *(const half8*)(W16 + (size_t)(n0 + bmm) * K + k0 + bseg * 8);
        __syncthreads();
        *(half8*)&As[amm * 32 + aseg * 8] = a0;
        *(half8*)&As[amm * 32 + (aseg + 2) * 8] = a1;
        *(half8*)&Bs[bmm * 32 + bseg * 8] = bv;
        __syncthreads();
        half8 af[2], bf[4];
#pragma unroll
        for (int fi = 0; fi < 2; ++fi)
            af[fi] = *(const half8*)&As[(w * 32 + fi * 16 + r16) * 32 + quad * 8];
#pragma unroll
        for (int fj = 0; fj < 4; ++fj)
            bf[fj] = *(const half8*)&Bs[(fj * 16 + r16) * 32 + quad * 8];
#pragma unroll
        for (int fi = 0; fi < 2; ++fi)
#pragma unroll
            for (int fj = 0; fj < 4; ++fj)
                acc[fi][fj] = __builtin_amdgcn_mfma_f32_16x16x32_f16(
                    af[fi], bf[fj], acc[fi][fj], 0, 0, 0);
    }
#pragma unroll
    for (int fi = 0; fi < 2; ++fi) {
#pragma unroll
        for (int r = 0; r < 4; ++r) {
            int m = m0 + w * 32 + fi * 16 + quad * 4 + r;
#pragma unroll
            for (int fj = 0; fj < 4; ++fj) {
                int n = n0 + fj * 16 + r16;
                float x = acc[fi][fj][r] + bias[n];
                C16[(size_t)m * HK + n] = (_Float16)fmaxf(x, 0.f);
            }
        }
    }
}

// ---------------------------------------------------------------------------
// att heads 0..8 via f16 MFMA. h<8 -> att_out fp32 (+hb[h], mask).
// h==8 (combined head) -> A16 f16 (+sum hb, mask).
// Block 128i x 64j, 4 waves.
// ---------------------------------------------------------------------------
__global__ __launch_bounds__(256) void att_mfma9(
    const _Float16* __restrict__ v16, const _Float16* __restrict__ q16,
    const _Float16* __restrict__ hs16, const float* __restrict__ hb,
    const float* __restrict__ vz, const float* __restrict__ qz,
    float* __restrict__ att_out, _Float16* __restrict__ A16) {
    __shared__ _Float16 As[128 * 32];
    __shared__ _Float16 Bs[64 * 32];
    int z = blockIdx.z;
    int b = z / 9, h = z - b * 9;
    int i0 = blockIdx.y * 128, j0 = blockIdx.x * 64;
    int t = threadIdx.x;
    int w = t >> 6, ln = t & 63, quad = ln >> 4, r16 = ln & 15;
    const _Float16* Vb = v16 + (size_t)b * VN * HK;
    const _Float16* Qb = q16 + (size_t)b * QN * HK;
    const _Float16* Hs = hs16 + (size_t)h * HK;
    int amm = t >> 1, aseg = t & 1;
    int bmm = t >> 2, bseg = t & 3;
    f32x4 acc[2][4] = {};
    for (int k0 = 0; k0 < HK; k0 += 32) {
        half8 a0 = *(const half8*)(Vb + (size_t)(i0 + amm) * HK + k0 + aseg * 8);
        half8 a1 = *(const half8*)(Vb + (size_t)(i0 + amm) * HK + k0 + (aseg + 2) * 8);
        half8 h0 = *(const half8*)(Hs + k0 + aseg * 8);
        half8 h1 = *(const half8*)(Hs + k0 + (aseg + 2) * 8);
        half8 bv = *(const half8*)(Qb + (size_t)(j0 + bmm) * HK + k0 + bseg * 8);
        a0 *= h0;
        a1 *= h1;
        __syncthreads();
        *(half8*)&As[amm * 32 + aseg * 8] = a0;
        *(half8*)&As[amm * 32 + (aseg + 2) * 8] = a1;
        *(half8*)&Bs[bmm * 32 + bseg * 8] = bv;
        __syncthreads();
        half8 af[2], bf[4];
#pragma unroll
        for (int fi = 0; fi < 2; ++fi)
            af[fi] = *(const half8*)&As[(w * 32 + fi * 16 + r16) * 32 + quad * 8];
#pragma unroll
        for (int fj = 0; fj < 4; ++fj)
            bf[fj] = *(const half8*)&Bs[(fj * 16 + r16) * 32 + quad * 8];
#pragma unroll
        for (int fi = 0; fi < 2; ++fi)
#pragma unroll
            for (int fj = 0; fj < 4; ++fj)
                acc[fi][fj] = __builtin_amdgcn_mfma_f32_16x16x32_f16(
                    af[fi], bf[fj], acc[fi][fj], 0, 0, 0);
    }
    float hbv;
    if (h < 8) {
        hbv = hb[h];
    } else {
        hbv = 0.f;
#pragma unroll
        for (int hh = 0; hh < 8; ++hh) hbv += hb[hh];
    }
    if (h < 8) {
        float* outb = att_out + ((size_t)(b * 8 + h)) * VN * QN;
#pragma unroll
        for (int fi = 0; fi < 2; ++fi) {
#pragma unroll
            for (int r = 0; r < 4; ++r) {
                int i = i0 + w * 32 + fi * 16 + quad * 4 + r;
                float vm = vz[b * VN + i];
#pragma unroll
                for (int fj = 0; fj < 4; ++fj) {
                    int j = j0 + fj * 16 + r16;
                    float x = acc[fi][fj][r] + hbv;
                    if (vm != 0.f || qz[b * QN + j] != 0.f) x = -INFINITY;
                    outb[(size_t)i * QN + j] = x;
                }
            }
        }
    } else {
        _Float16* Ab = A16 + (size_t)b * VN * QN;
#pragma unroll
        for (int fi = 0; fi < 2; ++fi) {
#pragma unroll
            for (int r = 0; r < 4; ++r) {
                int i = i0 + w * 32 + fi * 16 + quad * 4 + r;
                float vm = vz[b * VN + i];
#pragma unroll
                for (int fj = 0; fj < 4; ++fj) {
                    int j = j0 + fj * 16 + r16;
                    float x = acc[fi][fj][r] + hbv;
                    if (vm != 0.f || qz[b * QN + j] != 0.f) x = -INFINITY;
                    Ab[(size_t)i * QN + j] = (_Float16)x;
                }
            }
        }
    }
}

// ---------------------------------------------------------------------------
// q16t[b][k][j] = q16[b][j][k]  (per-batch transpose, 32j x 64k LDS tiles)
// ---------------------------------------------------------------------------
__global__ __launch_bounds__(256) void transpose_q16(const _Float16* __restrict__ q16,
                                                     _Float16* __restrict__ q16t) {
    __shared__ _Float16 Ls[32][72];
    int b = blockIdx.z;
    int k0 = blockIdx.x * 64, j0 = blockIdx.y * 32;
    int t = threadIdx.x;
    const _Float16* src = q16 + (size_t)b * QN * HK;
    int tj = t >> 3, tk = (t & 7) * 8;
    half8 vv = *(const half8*)(src + (size_t)(j0 + tj) * HK + k0 + tk);
#pragma unroll
    for (int e = 0; e < 8; ++e) Ls[tj][tk + e] = vv[e];
    __syncthreads();
    int ok = t >> 2, oj = (t & 3) * 8;
    half8 ov;
#pragma unroll
    for (int e = 0; e < 8; ++e) ov[e] = Ls[oj + e][ok];
    *(half8*)(q16t + (size_t)b * HK * QN + (size_t)(k0 + ok) * QN + j0 + oj) = ov;
}

// ---------------------------------------------------------------------------
// lk[b,k] = sum_i v16[b,i,k] * (sum_j A16[b,i,j] * q16t[b,k,j])
// One block per (k-tile of 64, b); i fully covered (4 waves x 64i each).
// ---------------------------------------------------------------------------
__global__ __launch_bounds__(256) void t_lk_mfma(
    const _Float16* __restrict__ A16, const _Float16* __restrict__ q16t,
    const _Float16* __restrict__ v16, float* __restrict__ lk) {
    __shared__ _Float16 As[256 * 32];
    __shared__ _Float16 Bs[64 * 32];
    __shared__ float red[16][64];
    int b = blockIdx.y;
    int k0 = blockIdx.x * 64;
    int t = threadIdx.x;
    int w = t >> 6, ln = t & 63, quad = ln >> 4, r16 = ln & 15;
    const _Float16* Ab = A16 + (size_t)b * VN * QN;
    const _Float16* Qt = q16t + (size_t)b * HK * QN + (size_t)k0 * QN;
    int ar = t >> 2, aseg = t & 3;
    f32x4 acc[4][4] = {};
    for (int j0 = 0; j0 < QN; j0 += 32) {
        half8 a0 = *(const half8*)(Ab + (size_t)(ar +   0) * QN + j0 + aseg * 8);
        half8 a1 = *(const half8*)(Ab + (size_t)(ar +  64) * QN + j0 + aseg * 8);
        half8 a2 = *(const half8*)(Ab + (size_t)(ar + 128) * QN + j0 + aseg * 8);
        half8 a3 = *(const half8*)(Ab + (size_t)(ar + 192) * QN + j0 + aseg * 8);
        half8 bv = *(const half8*)(Qt + (size_t)ar * QN + j0 + aseg * 8);
        __syncthreads();
        *(half8*)&As[(ar +   0) * 32 + aseg * 8] = a0;
        *(half8*)&As[(ar +  64) * 32 + aseg * 8] = a1;
        *(half8*)&As[(ar + 128) * 32 + aseg * 8] = a2;
        *(half8*)&As[(ar + 192) * 32 + aseg * 8] = a3;
        *(half8*)&Bs[ar * 32 + aseg * 8] = bv;
        __syncthreads();
        half8 af[4], bf[4];
#pragma unroll
        for (int fi = 0; fi < 4; ++fi)
            af[fi] = *(const half8*)&As[(w * 64 + fi * 16 + r16) * 32 + quad * 8];
#pragma unroll
        for (int fj = 0; fj < 4; ++fj)
            bf[fj] = *(const half8*)&Bs[(fj * 16 + r16) * 32 + quad * 8];
#pragma unroll
        for (int fi = 0; fi < 4; ++fi)
#pragma unroll
            for (int fj = 0; fj < 4; ++fj)
                acc[fi][fj] = __builtin_amdgcn_mfma_f32_16x16x32_f16(
                    af[fi], bf[fj], acc[fi][fj], 0, 0, 0);
    }
    const _Float16* Vb = v16 + (size_t)b * VN * HK;
    float part[4] = {0.f, 0.f, 0.f, 0.f};
#pragma unroll
    for (int fi = 0; fi < 4; ++fi) {
#pragma unroll
        for (int r = 0; r < 4; ++r) {
            int i = w * 64 + fi * 16 + quad * 4 + r;
#pragma unroll
            for (int fj = 0; fj < 4; ++fj) {
                float vv = (float)Vb[(size_t)i * HK + k0 + fj * 16 + r16];
                part[fj] += acc[fi][fj][r] * vv;
            }
        }
    }
#pragma unroll
    for (int fj = 0; fj < 4; ++fj)
        red[w * 4 + quad][fj * 16 + r16] = part[fj];
    __syncthreads();
    if (t < 64) {
        float s = 0.f;
#pragma unroll
        for (int g = 0; g < 16; ++g) s += red[g][t];
        lk[b * HK + k0 + t] = s;
    }
}

// ---------------------------------------------------------------------------
// pool(k=3, sum) + BatchNorm (batch stats, biased var)
// ---------------------------------------------------------------------------
__global__ __launch_bounds__(256) void bn_kernel(
    const float* __restrict__ lk, const float* __restrict__ gamma,
    const float* __restrict__ beta, float* __restrict__ out) {
    int d = blockIdx.x * blockDim.x + threadIdx.x;
    if (d >= HDIM) return;
    float l[BB];
    float mu = 0.f;
#pragma unroll
    for (int b = 0; b < BB; ++b) {
        const float* p = lk + b * HK + 3 * d;
        float s = p[0] + p[1] + p[2];
        l[b] = s;
        mu += s;
    }
    mu *= (1.f / BB);
    float var = 0.f;
#pragma unroll
    for (int b = 0; b < BB; ++b) {
        float dd = l[b] - mu;
        var += dd * dd;
    }
    var *= (1.f / BB);
    float inv = rsqrtf(var + 1e-5f);
    float g = gamma[d], be = beta[d];
#pragma unroll
    for (int b = 0; b < BB; ++b)
        out[b * HDIM + d] = (l[b] - mu) * inv * g + be;
}

// ---------------------------------------------------------------------------
extern "C" void kernel_launch(void* const* d_in, const int* in_sizes, int n_in,
                              void* d_out, int out_size, void* d_ws, size_t ws_size,
                              hipStream_t stream) {
    const float* v  = (const float*)d_in[0];
    const float* q  = (const float*)d_in[1];
    const float* Wv = (const float*)d_in[2];
    const float* bv = (const float*)d_in[3];
    const float* Wq = (const float*)d_in[4];
    const float* bq = (const float*)d_in[5];
    const float* hm = (const float*)d_in[6];
    const float* hb = (const float*)d_in[7];
    const float* gamma = (const float*)d_in[8];
    const float* beta  = (const float*)d_in[9];

    float* out_logits = (float*)d_out;
    float* out_att    = out_logits + BB * HDIM;

    // workspace layout (f16 elements unless noted)
    _Float16* h = (_Float16*)d_ws;
    _Float16* v16   = h;                                   // 16*256*1536
    _Float16* q16   = v16 + (size_t)BB * VN * HK;          // 16*256*1536
    _Float16* q16t  = q16 + (size_t)BB * QN * HK;          // 16*1536*256
    _Float16* A16   = q16t + (size_t)BB * HK * QN;         // 16*256*256
    _Float16* v16in = A16 + (size_t)BB * VN * QN;          // 16*256*512
    _Float16* q16in = v16in + (size_t)BB * VN * VD;        // 16*256*768
    _Float16* Wv16  = q16in + (size_t)BB * QN * QD;        // 1536*512
    _Float16* Wq16  = Wv16 + (size_t)HK * VD;              // 1536*768
    _Float16* hs16  = Wq16 + (size_t)HK * QD;              // 9*1536
    float* lk = (float*)(hs16 + 9 * HK + 8);               // 16*1536 f32
    float* vz = lk + BB * HK;
    float* qz = vz + BB * VN;

    // 1. conversions
    f32_to_f16_vec<<<(BB * VN * VD / 4 + 255) / 256, 256, 0, stream>>>(v, v16in, BB * VN * VD / 4);
    f32_to_f16_vec<<<(BB * QN * QD / 4 + 255) / 256, 256, 0, stream>>>(q, q16in, BB * QN * QD / 4);
    f32_to_f16_vec<<<(HK * VD / 4 + 255) / 256, 256, 0, stream>>>(Wv, Wv16, HK * VD / 4);
    f32_to_f16_vec<<<(HK * QD / 4 + 255) / 256, 256, 0, stream>>>(Wq, Wq16, HK * QD / 4);
    conv_hm9<<<(HK + 255) / 256, 256, 0, stream>>>(hm, hs16);

    // 2. masks
    mask_kernel<<<BB * VN, 64, 0, stream>>>(v, VD, vz);
    mask_kernel<<<BB * QN, 64, 0, stream>>>(q, QD, qz);

    // 3. projections -> v16, q16 (f16, relu)
    proj_mfma<<<dim3(HK / 64, BB * VN / 128), 256, 0, stream>>>(v16in, Wv16, bv, v16, VD);
    proj_mfma<<<dim3(HK / 64, BB * QN / 128), 256, 0, stream>>>(q16in, Wq16, bq, q16, QD);

    // 4. att heads 0..7 -> d_out; head 8 -> A16
    att_mfma9<<<dim3(QN / 64, VN / 128, BB * 9), 256, 0, stream>>>(
        v16, q16, hs16, hb, vz, qz, out_att, A16);

    // 5. q16t = transpose(q16)
    transpose_q16<<<dim3(HK / 64, QN / 32, BB), 256, 0, stream>>>(q16, q16t);

    // 6. lk = v16 . (A16 @ q16t^T)   fused
    t_lk_mfma<<<dim3(HK / 64, BB), 256, 0, stream>>>(A16, q16t, v16, lk);

    // 7. pool + batchnorm
    bn_kernel<<<dim3((HDIM + 255) / 256), 256, 0, stream>>>(lk, gamma, beta, out_logits);
}